// Round 3
// baseline (214.306 us; speedup 1.0000x reference)
//
#include <hip/hip_runtime.h>

// Inverse SWT (db4, 3 levels), T=4096, circular boundary.
// One block per output row; running result + current detail row live in LDS.
// v2: all 4 input rows prefetched into registers at kernel entry (HBM latency
// for cD2/cD1 hides under level-3/level-2 compute); barrier count 8 -> 5 by
// fusing "write new res" and "stage next hi" into one inter-barrier window.
// (Third submission — rounds 1 and 2 both died on broker/container infra with
// no kernel-side signal; kernel audited for hangs/OOB/divergent barriers: none.)

namespace {

constexpr int TT = 4096;       // time length
constexpr int T4 = TT / 4;     // in float4 units
constexpr int NT = 256;        // threads per block

// Compute one synthesis level at dilation D from LDS (res + hi) into acc[4].
// No staging, no barriers here — caller owns the sync structure.
template <int D>
__device__ __forceinline__ void level_compute(const float* lds_res,
                                              const float* lds_hi,
                                              int t, float4 acc[4]) {
  // db4 synthesis low-pass and QMF high-pass: hi[m] = (-1)^m * lo[7-m]
  constexpr float LO[8] = {
      0.23037781330885523f,  0.7148465705525415f,  0.6308807679295904f,
      -0.02798376941698385f, -0.18703481171888114f, 0.030841381835986965f,
      0.032883011666982945f, -0.010597401784997278f};
  constexpr float HI[8] = {
      -0.010597401784997278f, -0.032883011666982945f, 0.030841381835986965f,
      0.18703481171888114f,   -0.02798376941698385f,  -0.6308807679295904f,
      0.7148465705525415f,    -0.23037781330885523f};

  // Window for 4 contiguous outputs n0..n0+3 at dilation D:
  // taps span [n0-4D, n0+3+3D] -> 7D+4 floats, 16B-aligned since n0 % 4 == 0.
  constexpr int W4 = (7 * D + 7) / 4;  // float4 count: D=4 -> 8, D=2 -> 5, D=1 -> 3
  const float4* res4 = reinterpret_cast<const float4*>(lds_res);
  const float4* hir4 = reinterpret_cast<const float4*>(lds_hi);

#pragma unroll
  for (int g = 0; g < 4; ++g) {
    const int c = t + g * NT;  // float4 chunk index, 0..1023 (lane-consecutive)
    float w[4 * W4];

    // --- approximation (res) contribution ---
#pragma unroll
    for (int i = 0; i < W4; ++i) {
      const float4 v = res4[(c - D + i) & (T4 - 1)];
      w[4 * i + 0] = v.x; w[4 * i + 1] = v.y;
      w[4 * i + 2] = v.z; w[4 * i + 3] = v.w;
    }
    float a0 = 0.f, a1 = 0.f, a2 = 0.f, a3 = 0.f;
#pragma unroll
    for (int m = 0; m < 8; ++m) {
      const int o = D * (7 - m);  // w[o+j] == res[n0 + j - D*(m-3)]
      a0 += LO[m] * w[o + 0];
      a1 += LO[m] * w[o + 1];
      a2 += LO[m] * w[o + 2];
      a3 += LO[m] * w[o + 3];
    }

    // --- detail (hi) contribution ---
#pragma unroll
    for (int i = 0; i < W4; ++i) {
      const float4 v = hir4[(c - D + i) & (T4 - 1)];
      w[4 * i + 0] = v.x; w[4 * i + 1] = v.y;
      w[4 * i + 2] = v.z; w[4 * i + 3] = v.w;
    }
#pragma unroll
    for (int m = 0; m < 8; ++m) {
      const int o = D * (7 - m);
      a0 += HI[m] * w[o + 0];
      a1 += HI[m] * w[o + 1];
      a2 += HI[m] * w[o + 2];
      a3 += HI[m] * w[o + 3];
    }
    acc[g] = make_float4(0.5f * a0, 0.5f * a1, 0.5f * a2, 0.5f * a3);
  }
}

__global__ __launch_bounds__(NT, 4) void iswt_kernel(const float* __restrict__ x,
                                                     float* __restrict__ out) {
  __shared__ __align__(16) float lds_res[TT];
  __shared__ __align__(16) float lds_hi[TT];

  const int t = threadIdx.x;
  const int row = blockIdx.x;  // r = b*64 + n; input rows 4r..4r+3 = cA3,cD3,cD2,cD1

  const float4* xr4 = reinterpret_cast<const float4*>(x) + (size_t)row * 4 * T4;

  // Issue ALL global loads up front (16 float4 / thread, in flight together).
  // cA/cD3 are consumed immediately; cD2/cD1 latency hides under L3/L2 compute.
  float4 rA[4], rH3[4], rH2[4], rH1[4];
#pragma unroll
  for (int k = 0; k < 4; ++k) rA[k]  = xr4[0 * T4 + t + k * NT];
#pragma unroll
  for (int k = 0; k < 4; ++k) rH3[k] = xr4[1 * T4 + t + k * NT];
#pragma unroll
  for (int k = 0; k < 4; ++k) rH2[k] = xr4[2 * T4 + t + k * NT];
#pragma unroll
  for (int k = 0; k < 4; ++k) rH1[k] = xr4[3 * T4 + t + k * NT];

  float4* res4 = reinterpret_cast<float4*>(lds_res);
  float4* hiw4 = reinterpret_cast<float4*>(lds_hi);

  // Stage cA -> res, cD3 -> hi.
#pragma unroll
  for (int k = 0; k < 4; ++k) res4[t + k * NT] = rA[k];
#pragma unroll
  for (int k = 0; k < 4; ++k) hiw4[t + k * NT] = rH3[k];
  __syncthreads();  // (1) stage visible

  float4 acc[4];

  // ---- level 3 (D=4) ----
  level_compute<4>(lds_res, lds_hi, t, acc);
  __syncthreads();  // (2) all LDS reads done
#pragma unroll
  for (int k = 0; k < 4; ++k) {
    res4[t + k * NT] = acc[k];   // new approximation
    hiw4[t + k * NT] = rH2[k];   // stage next detail (already in regs)
  }
  __syncthreads();  // (3) writes visible

  // ---- level 2 (D=2) ----
  level_compute<2>(lds_res, lds_hi, t, acc);
  __syncthreads();  // (4)
#pragma unroll
  for (int k = 0; k < 4; ++k) {
    res4[t + k * NT] = acc[k];
    hiw4[t + k * NT] = rH1[k];
  }
  __syncthreads();  // (5)

  // ---- level 1 (D=1) ---- result goes straight to global; no trailing sync.
  level_compute<1>(lds_res, lds_hi, t, acc);
  float4* out4 = reinterpret_cast<float4*>(out) + (size_t)row * T4;
#pragma unroll
  for (int k = 0; k < 4; ++k) out4[t + k * NT] = acc[k];
}

}  // namespace

extern "C" void kernel_launch(void* const* d_in, const int* in_sizes, int n_in,
                              void* d_out, int out_size, void* d_ws, size_t ws_size,
                              hipStream_t stream) {
  const float* x = reinterpret_cast<const float*>(d_in[0]);
  float* out = reinterpret_cast<float*>(d_out);
  const int rows = out_size / TT;  // B*N = 2048
  iswt_kernel<<<rows, NT, 0, stream>>>(x, out);
}

// Round 4
// 201.241 us; speedup vs baseline: 1.0649x; 1.0649x over previous
//
#include <hip/hip_runtime.h>

// Inverse SWT (db4, 3 levels), T=4096, circular boundary.
// v3: async global->LDS staging via global_load_lds(16B) with COUNTED vmcnt
// waits + raw s_barrier (no __syncthreads: it drains vmcnt(0) and kills the
// pipeline). Triple-buffered detail rows (res + hiA + hiB = 48 KiB -> 3
// blocks/CU). cD2 streams in under level-3 compute, cD1 under level-2.
// v2 post-mortem: "register prefetch" of cD2/cD1 spilled to scratch
// (VGPR=52 proves regs weren't held; WRITE_SIZE 96 MiB = 32 out + 64 spill).
// DMA staging uses zero VGPRs -> no spill possible.

namespace {

constexpr int TT = 4096;       // time length
constexpr int T4 = TT / 4;     // in float4 units
constexpr int NT = 256;        // threads per block

// Async 16B global->LDS DMA. LDS dest is wave-uniform base + lane*16, which
// our lane-contiguous mapping satisfies exactly (lane l stages bytes l*16 of
// its wave's 1 KiB chunk).
#define GLD16(gp, lp)                                                      \
  __builtin_amdgcn_global_load_lds(                                        \
      (const __attribute__((address_space(1))) void*)(gp),                 \
      (__attribute__((address_space(3))) void*)(lp), 16, 0, 0)

// Compute one synthesis level at dilation D from LDS (res + hi) into acc[4].
// No staging, no barriers here — caller owns the sync structure.
template <int D>
__device__ __forceinline__ void level_compute(const float* lds_res,
                                              const float* lds_hi,
                                              int t, float4 acc[4]) {
  // db4 synthesis low-pass and QMF high-pass: hi[m] = (-1)^m * lo[7-m]
  constexpr float LO[8] = {
      0.23037781330885523f,  0.7148465705525415f,  0.6308807679295904f,
      -0.02798376941698385f, -0.18703481171888114f, 0.030841381835986965f,
      0.032883011666982945f, -0.010597401784997278f};
  constexpr float HI[8] = {
      -0.010597401784997278f, -0.032883011666982945f, 0.030841381835986965f,
      0.18703481171888114f,   -0.02798376941698385f,  -0.6308807679295904f,
      0.7148465705525415f,    -0.23037781330885523f};

  // Window for 4 contiguous outputs n0..n0+3 at dilation D:
  // taps span [n0-4D, n0+3+3D] -> 7D+4 floats, 16B-aligned since n0 % 4 == 0.
  constexpr int W4 = (7 * D + 7) / 4;  // float4 count: D=4 -> 8, D=2 -> 5, D=1 -> 3
  const float4* res4 = reinterpret_cast<const float4*>(lds_res);
  const float4* hir4 = reinterpret_cast<const float4*>(lds_hi);

#pragma unroll
  for (int g = 0; g < 4; ++g) {
    const int c = t + g * NT;  // float4 chunk index, 0..1023 (lane-consecutive)
    float w[4 * W4];

    // --- approximation (res) contribution ---
#pragma unroll
    for (int i = 0; i < W4; ++i) {
      const float4 v = res4[(c - D + i) & (T4 - 1)];
      w[4 * i + 0] = v.x; w[4 * i + 1] = v.y;
      w[4 * i + 2] = v.z; w[4 * i + 3] = v.w;
    }
    float a0 = 0.f, a1 = 0.f, a2 = 0.f, a3 = 0.f;
#pragma unroll
    for (int m = 0; m < 8; ++m) {
      const int o = D * (7 - m);  // w[o+j] == res[n0 + j - D*(m-3)]
      a0 += LO[m] * w[o + 0];
      a1 += LO[m] * w[o + 1];
      a2 += LO[m] * w[o + 2];
      a3 += LO[m] * w[o + 3];
    }

    // --- detail (hi) contribution ---
#pragma unroll
    for (int i = 0; i < W4; ++i) {
      const float4 v = hir4[(c - D + i) & (T4 - 1)];
      w[4 * i + 0] = v.x; w[4 * i + 1] = v.y;
      w[4 * i + 2] = v.z; w[4 * i + 3] = v.w;
    }
#pragma unroll
    for (int m = 0; m < 8; ++m) {
      const int o = D * (7 - m);
      a0 += HI[m] * w[o + 0];
      a1 += HI[m] * w[o + 1];
      a2 += HI[m] * w[o + 2];
      a3 += HI[m] * w[o + 3];
    }
    acc[g] = make_float4(0.5f * a0, 0.5f * a1, 0.5f * a2, 0.5f * a3);
  }
}

__global__ __launch_bounds__(NT) void iswt_kernel(const float* __restrict__ x,
                                                  float* __restrict__ out) {
  __shared__ __align__(16) float lds_res[TT];
  __shared__ __align__(16) float lds_hiA[TT];
  __shared__ __align__(16) float lds_hiB[TT];

  const int t = threadIdx.x;
  const int row = blockIdx.x;  // r = b*64 + n; input rows 4r..4r+3 = cA3,cD3,cD2,cD1

  const float* xr = x + (size_t)row * 4 * TT;

  // Issue 12 async DMA loads in FIFO order: cA(4) -> res, cD3(4) -> hiA,
  // cD2(4) -> hiB. vmcnt(4) below leaves only the 4 newest (cD2) possibly
  // outstanding: cD2's HBM latency hides under level-3 compute.
#pragma unroll
  for (int k = 0; k < 4; ++k)
    GLD16(xr + 0 * TT + (t + k * NT) * 4, lds_res + (t + k * NT) * 4);
#pragma unroll
  for (int k = 0; k < 4; ++k)
    GLD16(xr + 1 * TT + (t + k * NT) * 4, lds_hiA + (t + k * NT) * 4);
#pragma unroll
  for (int k = 0; k < 4; ++k)
    GLD16(xr + 2 * TT + (t + k * NT) * 4, lds_hiB + (t + k * NT) * 4);

  // cA + cD3 landed (per-wave), then rendezvous: all waves' chunks visible.
  asm volatile("s_waitcnt vmcnt(4)\n\ts_barrier" ::: "memory");

  float4 acc[4];
  float4* res4 = reinterpret_cast<float4*>(lds_res);

  // ---- level 3 (D=4): res=cA, hi=cD3; cD2 streaming into hiB meanwhile ----
  level_compute<4>(lds_res, lds_hiA, t, acc);
  // All waves done READING res & hiA (lgkmcnt(0) retires this wave's ds ops;
  // barrier makes it collective) before we overwrite either buffer.
  asm volatile("s_waitcnt lgkmcnt(0)\n\ts_barrier" ::: "memory");

  // Reuse hiA for cD1 (DMA, streams in under level-2 compute); write new res.
#pragma unroll
  for (int k = 0; k < 4; ++k)
    GLD16(xr + 3 * TT + (t + k * NT) * 4, lds_hiA + (t + k * NT) * 4);
#pragma unroll
  for (int k = 0; k < 4; ++k) res4[t + k * NT] = acc[k];

  // vmcnt(4): all initial 12 done (cD2 landed), only cD1's 4 may remain.
  // lgkmcnt(0): this wave's res writes in LDS.
  asm volatile("s_waitcnt vmcnt(4) lgkmcnt(0)\n\ts_barrier" ::: "memory");

  // ---- level 2 (D=2): res, hi=cD2; cD1 streaming into hiA meanwhile ----
  level_compute<2>(lds_res, lds_hiB, t, acc);
  asm volatile("s_waitcnt lgkmcnt(0)\n\ts_barrier" ::: "memory");

#pragma unroll
  for (int k = 0; k < 4; ++k) res4[t + k * NT] = acc[k];

  // cD1 fully landed + res writes visible.
  asm volatile("s_waitcnt vmcnt(0) lgkmcnt(0)\n\ts_barrier" ::: "memory");

  // ---- level 1 (D=1): straight to global, no trailing sync ----
  level_compute<1>(lds_res, lds_hiA, t, acc);
  float4* out4 = reinterpret_cast<float4*>(out) + (size_t)row * T4;
#pragma unroll
  for (int k = 0; k < 4; ++k) out4[t + k * NT] = acc[k];
}

}  // namespace

extern "C" void kernel_launch(void* const* d_in, const int* in_sizes, int n_in,
                              void* d_out, int out_size, void* d_ws, size_t ws_size,
                              hipStream_t stream) {
  const float* x = reinterpret_cast<const float*>(d_in[0]);
  float* out = reinterpret_cast<float*>(d_out);
  const int rows = out_size / TT;  // B*N = 2048
  iswt_kernel<<<rows, NT, 0, stream>>>(x, out);
}

// Round 5
// 199.292 us; speedup vs baseline: 1.0753x; 1.0098x over previous
//
#include <hip/hip_runtime.h>

// Inverse SWT (db4, 3 levels), T=4096, circular boundary.
// v4: occupancy fix. v3 post-mortem showed the kernel stuck at ~44 us (total
// 201 = 2x78.6 fill + kernel) with only ~33% occupancy (12 waves/CU): 4-wave
// blocks spend their life at barrier joins, too few runnable waves to keep
// HBM saturated. New shape: 1024 threads/block (16 waves), one float4 chunk
// per thread per level, ALL FOUR rows DMA-staged into 64 KiB LDS up front
// with counted vmcnt waits. 2 blocks/CU = 32 waves = 100% wave occupancy
// (needs VGPR<=64, enforced; per-thread state is ~50 VGPR).
// Arithmetic per output identical to the passing kernel -> bit-identical.

namespace {

constexpr int TT = 4096;       // time length
constexpr int T4 = TT / 4;     // in float4 units
constexpr int NT = 1024;       // threads per block (16 waves)

// Async 16B global->LDS DMA: LDS dest = wave-uniform base + lane*16, which the
// lane-contiguous chunk mapping satisfies exactly.
#define GLD16(gp, lp)                                                      \
  __builtin_amdgcn_global_load_lds(                                        \
      (const __attribute__((address_space(1))) void*)(gp),                 \
      (__attribute__((address_space(3))) void*)(lp), 16, 0, 0)

// One synthesis level at dilation D: thread computes outputs 4c..4c+3 from
// LDS res+hi. Same unpack + m-loop order as the verified kernel.
template <int D>
__device__ __forceinline__ float4 level_compute(const float* lds_res,
                                                const float* lds_hi, int c) {
  // db4 synthesis low-pass and QMF high-pass: hi[m] = (-1)^m * lo[7-m]
  constexpr float LO[8] = {
      0.23037781330885523f,  0.7148465705525415f,  0.6308807679295904f,
      -0.02798376941698385f, -0.18703481171888114f, 0.030841381835986965f,
      0.032883011666982945f, -0.010597401784997278f};
  constexpr float HI[8] = {
      -0.010597401784997278f, -0.032883011666982945f, 0.030841381835986965f,
      0.18703481171888114f,   -0.02798376941698385f,  -0.6308807679295904f,
      0.7148465705525415f,    -0.23037781330885523f};

  // Window for 4 contiguous outputs at dilation D: 7D+4 floats, 16B-aligned.
  constexpr int W4 = (7 * D + 7) / 4;  // D=4 -> 8, D=2 -> 5, D=1 -> 3
  const float4* res4 = reinterpret_cast<const float4*>(lds_res);
  const float4* hir4 = reinterpret_cast<const float4*>(lds_hi);

  float w[4 * W4];

  // --- approximation (res) contribution ---
#pragma unroll
  for (int i = 0; i < W4; ++i) {
    const float4 v = res4[(c - D + i) & (T4 - 1)];
    w[4 * i + 0] = v.x; w[4 * i + 1] = v.y;
    w[4 * i + 2] = v.z; w[4 * i + 3] = v.w;
  }
  float a0 = 0.f, a1 = 0.f, a2 = 0.f, a3 = 0.f;
#pragma unroll
  for (int m = 0; m < 8; ++m) {
    const int o = D * (7 - m);  // w[o+j] == res[n0 + j - D*(m-3)]
    a0 += LO[m] * w[o + 0];
    a1 += LO[m] * w[o + 1];
    a2 += LO[m] * w[o + 2];
    a3 += LO[m] * w[o + 3];
  }

  // --- detail (hi) contribution ---
#pragma unroll
  for (int i = 0; i < W4; ++i) {
    const float4 v = hir4[(c - D + i) & (T4 - 1)];
    w[4 * i + 0] = v.x; w[4 * i + 1] = v.y;
    w[4 * i + 2] = v.z; w[4 * i + 3] = v.w;
  }
#pragma unroll
  for (int m = 0; m < 8; ++m) {
    const int o = D * (7 - m);
    a0 += HI[m] * w[o + 0];
    a1 += HI[m] * w[o + 1];
    a2 += HI[m] * w[o + 2];
    a3 += HI[m] * w[o + 3];
  }
  return make_float4(0.5f * a0, 0.5f * a1, 0.5f * a2, 0.5f * a3);
}

__global__ __launch_bounds__(NT, 8) void iswt_kernel(const float* __restrict__ x,
                                                     float* __restrict__ out) {
  __shared__ __align__(16) float lds_res[TT];  // cA, then running result
  __shared__ __align__(16) float lds_h3[TT];
  __shared__ __align__(16) float lds_h2[TT];
  __shared__ __align__(16) float lds_h1[TT];   // 64 KiB total -> 2 blocks/CU

  const int t = threadIdx.x;   // == float4 chunk index, 0..1023
  const int row = blockIdx.x;  // input rows 4r..4r+3 = cA3, cD3, cD2, cD1

  const float* xr = x + (size_t)row * 4 * TT;

  // Issue all 4 DMA loads (1 per row per thread), FIFO order. Counted waits
  // below expose each buffer exactly when its level needs it.
  GLD16(xr + 0 * TT + t * 4, lds_res + t * 4);
  GLD16(xr + 1 * TT + t * 4, lds_h3 + t * 4);
  GLD16(xr + 2 * TT + t * 4, lds_h2 + t * 4);
  GLD16(xr + 3 * TT + t * 4, lds_h1 + t * 4);

  float4* res4 = reinterpret_cast<float4*>(lds_res);

  // cA + cD3 landed (2 newest — cD2, cD1 — may still be in flight).
  asm volatile("s_waitcnt vmcnt(2)\n\ts_barrier" ::: "memory");

  // ---- level 3 (D=4) ----
  float4 acc = level_compute<4>(lds_res, lds_h3, t);
  asm volatile("s_waitcnt lgkmcnt(0)\n\ts_barrier" ::: "memory");  // reads done
  res4[t] = acc;
  // cD2 landed + this wave's res write retired; barrier makes both collective.
  asm volatile("s_waitcnt vmcnt(1) lgkmcnt(0)\n\ts_barrier" ::: "memory");

  // ---- level 2 (D=2) ----
  acc = level_compute<2>(lds_res, lds_h2, t);
  asm volatile("s_waitcnt lgkmcnt(0)\n\ts_barrier" ::: "memory");
  res4[t] = acc;
  // cD1 landed + res write visible.
  asm volatile("s_waitcnt vmcnt(0) lgkmcnt(0)\n\ts_barrier" ::: "memory");

  // ---- level 1 (D=1): straight to global, no trailing sync ----
  acc = level_compute<1>(lds_res, lds_h1, t);
  reinterpret_cast<float4*>(out)[(size_t)row * T4 + t] = acc;
}

}  // namespace

extern "C" void kernel_launch(void* const* d_in, const int* in_sizes, int n_in,
                              void* d_out, int out_size, void* d_ws, size_t ws_size,
                              hipStream_t stream) {
  const float* x = reinterpret_cast<const float*>(d_in[0]);
  float* out = reinterpret_cast<float*>(d_out);
  const int rows = out_size / TT;  // B*N = 2048
  iswt_kernel<<<rows, NT, 0, stream>>>(x, out);
}

// Round 6
// 196.713 us; speedup vs baseline: 1.0894x; 1.0131x over previous
//
#include <hip/hip_runtime.h>

// Inverse SWT (db4, 3 levels), T=4096, circular boundary.
// v5: LDS-traffic cut. v0/v3/v4 all land at ~44 us kernel time despite
// occupancy 33->100% and DMA pipelining changes. Per-CU accounting fits
// 44 us = 24 us HBM + 20 us LDS-read (serialized by the barrier structure).
// This version halves LDS reads: each thread computes 2 CONSECUTIVE float4
// chunks (8 outputs), sharing one tap window (76 vs 128 b128 reads per 16
// outputs). Consecutive-chunk reads are bank-conflicted at lane stride 32 B,
// so chunks live at XOR-swizzled slots slot=c^((c>>3)&7) (involution,
// permutes within 64-chunk blocks only): DMA keeps a LINEAR LDS dest and
// pre-swizzles the per-lane GLOBAL source (m173 pattern); all LDS reads/
// writes use swizzled slots. Output bounces through free LDS (h3) so the
// final global store stays chunk-coalesced.
// Per-output FMA order identical to the verified kernel -> bit-identical.

namespace {

constexpr int TT = 4096;       // time length (floats)
constexpr int T4 = TT / 4;     // float4 chunks per row
constexpr int NT = 512;        // threads per block (8 waves)
constexpr int NCH = 2;         // consecutive chunks per thread (8 outputs)

// Async 16B global->LDS DMA (LDS dest wave-uniform base + lane*16; our slot
// mapping is linear in lane, so per-lane pointer arithmetic is valid).
#define GLD16(gp, lp)                                                      \
  __builtin_amdgcn_global_load_lds(                                        \
      (const __attribute__((address_space(1))) void*)(gp),                 \
      (__attribute__((address_space(3))) void*)(lp), 16, 0, 0)

// Swizzled LDS slot for logical chunk c (bits 0-2 ^= bits 3-5): involution,
// bijective, spreads lane-stride-2-chunk accesses across all bank groups.
__device__ __forceinline__ int sl(int c) {
  c &= (T4 - 1);
  return c ^ ((c >> 3) & 7);
}

// One synthesis level at dilation D: thread u computes output chunks
// NCH*u .. NCH*u+NCH-1 from swizzled LDS res+hi. Same per-output unpack and
// m-loop order as the verified kernel (bit-identical results).
template <int D>
__device__ __forceinline__ void level_compute(const float* lds_res,
                                              const float* lds_hi, int u,
                                              float4 acc[NCH]) {
  constexpr float LO[8] = {
      0.23037781330885523f,  0.7148465705525415f,  0.6308807679295904f,
      -0.02798376941698385f, -0.18703481171888114f, 0.030841381835986965f,
      0.032883011666982945f, -0.010597401784997278f};
  constexpr float HI[8] = {
      -0.010597401784997278f, -0.032883011666982945f, 0.030841381835986965f,
      0.18703481171888114f,   -0.02798376941698385f,  -0.6308807679295904f,
      0.7148465705525415f,    -0.23037781330885523f};

  // Window for 4*NCH contiguous outputs: 7D + 4*NCH floats starting at
  // n0 - 4D (chunk-aligned for D in {1,2,4} since n0 = 4*NCH*u).
  constexpr int W4 = (7 * D + 4 * NCH + 3) / 4;  // D=4 -> 9, D=2 -> 6, D=1 -> 4
  const float4* res4 = reinterpret_cast<const float4*>(lds_res);
  const float4* hir4 = reinterpret_cast<const float4*>(lds_hi);
  const int c0 = NCH * u - D;  // first window chunk

  float w[4 * W4];
  float a[NCH][4];

  // --- approximation (res) contribution ---
#pragma unroll
  for (int i = 0; i < W4; ++i) {
    const float4 v = res4[sl(c0 + i)];
    w[4 * i + 0] = v.x; w[4 * i + 1] = v.y;
    w[4 * i + 2] = v.z; w[4 * i + 3] = v.w;
  }
#pragma unroll
  for (int jc = 0; jc < NCH; ++jc)
#pragma unroll
    for (int r = 0; r < 4; ++r) a[jc][r] = 0.f;
#pragma unroll
  for (int m = 0; m < 8; ++m) {
    const int o = D * (7 - m);  // w[o+j] == res[n0 + j - D*(m-3)]
#pragma unroll
    for (int jc = 0; jc < NCH; ++jc)
#pragma unroll
      for (int r = 0; r < 4; ++r) a[jc][r] += LO[m] * w[o + 4 * jc + r];
  }

  // --- detail (hi) contribution ---
#pragma unroll
  for (int i = 0; i < W4; ++i) {
    const float4 v = hir4[sl(c0 + i)];
    w[4 * i + 0] = v.x; w[4 * i + 1] = v.y;
    w[4 * i + 2] = v.z; w[4 * i + 3] = v.w;
  }
#pragma unroll
  for (int m = 0; m < 8; ++m) {
    const int o = D * (7 - m);
#pragma unroll
    for (int jc = 0; jc < NCH; ++jc)
#pragma unroll
      for (int r = 0; r < 4; ++r) a[jc][r] += HI[m] * w[o + 4 * jc + r];
  }

#pragma unroll
  for (int jc = 0; jc < NCH; ++jc)
    acc[jc] = make_float4(0.5f * a[jc][0], 0.5f * a[jc][1],
                          0.5f * a[jc][2], 0.5f * a[jc][3]);
}

__global__ __launch_bounds__(NT, 4) void iswt_kernel(const float* __restrict__ x,
                                                     float* __restrict__ out) {
  __shared__ __align__(16) float lds_res[TT];  // cA, then running result
  __shared__ __align__(16) float lds_h3[TT];   // cD3; reused as store bounce
  __shared__ __align__(16) float lds_h2[TT];
  __shared__ __align__(16) float lds_h1[TT];   // 64 KiB -> 2 blocks/CU

  const int t = threadIdx.x;
  const int row = blockIdx.x;  // input rows 4r..4r+3 = cA3, cD3, cD2, cD1

  const float* xr = x + (size_t)row * 4 * TT;

  // DMA-stage all 4 rows: linear LDS slots, pre-swizzled global source
  // (slot s receives chunk sl(s); sl is an involution and permutes only
  // within 64-chunk blocks -> wave fetches stay fully coalesced).
  // Issue order res,h3,h2,h1 (2 instrs each) for counted vmcnt below.
#pragma unroll
  for (int k = 0; k < NCH; ++k) {
    const int s = k * NT + t;
    GLD16(xr + 0 * TT + sl(s) * 4, lds_res + s * 4);
  }
#pragma unroll
  for (int k = 0; k < NCH; ++k) {
    const int s = k * NT + t;
    GLD16(xr + 1 * TT + sl(s) * 4, lds_h3 + s * 4);
  }
#pragma unroll
  for (int k = 0; k < NCH; ++k) {
    const int s = k * NT + t;
    GLD16(xr + 2 * TT + sl(s) * 4, lds_h2 + s * 4);
  }
#pragma unroll
  for (int k = 0; k < NCH; ++k) {
    const int s = k * NT + t;
    GLD16(xr + 3 * TT + sl(s) * 4, lds_h1 + s * 4);
  }

  float4* res4 = reinterpret_cast<float4*>(lds_res);
  float4 acc[NCH];

  // cA + cD3 landed (4 newest — cD2, cD1 — may still be in flight).
  asm volatile("s_waitcnt vmcnt(4)\n\ts_barrier" ::: "memory");

  // ---- level 3 (D=4); cD2/cD1 streaming meanwhile ----
  level_compute<4>(lds_res, lds_h3, t, acc);
  asm volatile("s_waitcnt lgkmcnt(0)\n\ts_barrier" ::: "memory");  // reads done
#pragma unroll
  for (int jc = 0; jc < NCH; ++jc) res4[sl(NCH * t + jc)] = acc[jc];
  // cD2 landed + this wave's res writes retired; barrier -> collective.
  asm volatile("s_waitcnt vmcnt(2) lgkmcnt(0)\n\ts_barrier" ::: "memory");

  // ---- level 2 (D=2); cD1 streaming meanwhile ----
  level_compute<2>(lds_res, lds_h2, t, acc);
  asm volatile("s_waitcnt lgkmcnt(0)\n\ts_barrier" ::: "memory");
#pragma unroll
  for (int jc = 0; jc < NCH; ++jc) res4[sl(NCH * t + jc)] = acc[jc];
  asm volatile("s_waitcnt vmcnt(0) lgkmcnt(0)\n\ts_barrier" ::: "memory");

  // ---- level 1 (D=1) ----
  level_compute<1>(lds_res, lds_h1, t, acc);

  // Store bounce through h3 (free since level 3): de-swizzle so the global
  // store is chunk-coalesced (direct store from acc would be stride-32B).
  float4* bounce4 = reinterpret_cast<float4*>(lds_h3);
#pragma unroll
  for (int jc = 0; jc < NCH; ++jc) bounce4[sl(NCH * t + jc)] = acc[jc];
  asm volatile("s_waitcnt lgkmcnt(0)\n\ts_barrier" ::: "memory");

  float4* out4 = reinterpret_cast<float4*>(out) + (size_t)row * T4;
#pragma unroll
  for (int k = 0; k < NCH; ++k) {
    const int c = k * NT + t;
    out4[c] = bounce4[sl(c)];
  }
}

}  // namespace

extern "C" void kernel_launch(void* const* d_in, const int* in_sizes, int n_in,
                              void* d_out, int out_size, void* d_ws, size_t ws_size,
                              hipStream_t stream) {
  const float* x = reinterpret_cast<const float*>(d_in[0]);
  float* out = reinterpret_cast<float*>(d_out);
  const int rows = out_size / TT;  // B*N = 2048
  iswt_kernel<<<rows, NT, 0, stream>>>(x, out);
}